// Round 3
// 295.920 us; speedup vs baseline: 1.0167x; 1.0167x over previous
//
#include <hip/hip_runtime.h>

// Exact-order float32 arithmetic: numpy/jax evaluate left-to-right with no
// FMA contraction. hipcc defaults to -ffp-contract=fast, which would change
// rounding -> possible spike-time shift -> large voltage absmax error.
#pragma clang fp contract(off)

// R16 = R14's "select the already-computed speculation, don't recompute the
// tail" structure, expressed in plain C (no inline asm). R15's "s"-constraint
// cndmask failed to compile: clang's divergence analysis demoted the 64-bit
// masks to VGPR pairs. Here all selects are per-lane bools:
//   - pairs quad-adjacent: EBN(0,1) IFN(2,3) TN(4,5) MN(6,7) LLBN(8)
//     -> partner candidate v1 via one DPP quad_perm:[1,0,3,2]
//   - own fire fa = (v1>=30), partner fire fap = (v1p>=30): LOCAL compares
//   - both variants finalized: wv=fa?c:v1, wvp=fap?c:v1p, uc/ucp from the
//     pair-identical u1/u1d
//   - uniform SALU resolve (bit extracts + 3 cselects, no dynamic shifts)
//     builds pm32 = "take partner" mask; per-lane pick via
//     take_p = (pm32 & lane_bit)!=0  -> v_and + v_cmp + 3x v_cndmask
//   - speculative I: fixed per lane (EBN/IFN/MN), uniform z5 ternary (TN),
//     uniform z2/z4 ternary chain + isLLBN lane-mask select (LLBN)
// Every selected value is produced by the identical f32 op sequence as
// R9/R13 (pair lanes hold bitwise-identical v,u) -> absmax 0.0. Detection
// semantics (rolling-40 anchor at block-counter wrap + Brent pow-2
// fallback), flush, and fill_cycle are R13 verbatim. Pair lanes write
// duplicate identical values to the same output row (benign).

// swap lanes within pairs (0<->1, 2<->3, ...): quad_perm [1,0,3,2] = 0xB1.
// Lane 8 reads inactive lane 9 -> old(=0); never selected (pm bit8 == 0).
__device__ __forceinline__ float dpp_swap1(float x) {
    return __int_as_float(__builtin_amdgcn_update_dpp(
        0, __float_as_int(x), 0xB1, 0xF, 0xF, true));
}

__global__ __launch_bounds__(256) void net_sim(const float* __restrict__ mat,
                                               const float* __restrict__ w,
                                               float* __restrict__ out,
                                               int* __restrict__ ws,
                                               int T) {
    __shared__ double red[256];
    const int tid = threadIdx.x;

    // ---- z_plus = sum(input_mat * w0), f32 products accumulated in f64 ----
    // (summation order must stay EXACT: strided partials + fixed tree)
    const float w0 = w[0];
    double s = 0.0;
    for (int i = tid; i < 127 * 127; i += 256) {
        float p = mat[i] * w0;   // elementwise product rounded to f32 (as ref)
        s += (double)p;
    }
    red[tid] = s;
    __syncthreads();
    #pragma unroll
    for (int off = 128; off > 0; off >>= 1) {
        if (tid < off) red[tid] += red[tid + off];
        __syncthreads();
    }
    if (tid >= 9) return;   // 9 lanes of wave 0 continue; no more barriers

    const float z_plus = (float)red[0];

    const float w2 = w[2], w3 = w[3], w5 = w[5], w6 = w[6], w7 = w[7],
                w8 = w[8], w9 = w[9], w10 = w[10], w11 = w[11];
    const float zp_w1 = z_plus * w[1];
    const float zp_w4 = z_plus * w[4];

    // Validated constant-I set (R2..R13, absmax 0.0). z*w is exactly +0.0f
    // or w; x + (+0.0f) == x for the values involved.
    const float I2_00 = w2 * (zp_w1 - 0.0f) + w3 * 0.0f;   // (z2p, z4p)
    const float I2_10 = w2 * (zp_w1 - 0.0f) + w3 * 1.0f;
    const float I2_01 = w2 * (zp_w1 - w7)   + w3 * 0.0f;
    const float I2_11 = w2 * (zp_w1 - w7)   + w3 * 1.0f;
    const float I3_0  = zp_w4 + 0.0f * w5;
    const float I3_1  = zp_w4 + 1.0f * w5;
    const float I4_0  = 0.0f * w6;
    const float I4_1  = 1.0f * w6;
    const float I5_00 = w9 * (0.0f * w8) + w10 * 0.0f;     // (z3, z5p)
    const float I5_10 = w9 * (1.0f * w8) + w10 * 0.0f;
    const float I5_01 = w9 * (0.0f * w8) + w10 * 1.0f;
    const float I5_11 = w9 * (1.0f * w8) + w10 * 1.0f;
    const float I6_0  = 0.0f * w11;
    const float I6_1  = 1.0f * w11;

    // Lane map: 0,1=EBN(z2=0/1)  2,3=IFN(z3=0/1)  4,5=TN(z3=0/1)
    //           6,7=MN(z5=0/1)   8=LLBN (no speculation)
    const int lane = tid;                  // 0..8
    const bool isLLBN = (lane == 8);
    const bool isTN   = ((lane >> 1) == 2);
    const int g = isLLBN ? 0 : 1 + (lane >> 1);   // output row
    const unsigned lane_bit = 1u << lane;

    // per-lane params; ka = float(TAU*DT*a) computed in f64 like Python
    const float ka = isLLBN ? (float)(0.25 * 0.1) : (float)(0.25 * 0.02);
    const float b  = isLLBN ? -0.075f : (isTN ? 0.2f : 0.25f);
    const float c  = (isLLBN || g == 1) ? -55.0f : -65.0f;
    const float d  = (g == 1) ? 0.05f : 6.0f;
    float v = isLLBN ? -60.0f : (isTN ? -70.0f : -64.0f);
    float u = isLLBN ? 4.5f   : (isTN ? -14.0f : -16.0f);

    // fixed speculative currents; _b differs from _a only for TN (z5p=1)
    const float Ib_a =
        lane == 0 ? I3_0 : lane == 1 ? I3_1 :
        lane == 2 ? I4_0 : lane == 3 ? I4_1 :
        lane == 4 ? I5_00 : lane == 5 ? I5_10 :
        lane == 6 ? I6_0 : lane == 7 ? I6_1 : I2_00;
    const float Ib_b = lane == 4 ? I5_01 : lane == 5 ? I5_11 : Ib_a;

    float* __restrict__ psp = out + g * T;           // spikes row
    float* __restrict__ pvv = out + 5 * T + g * T;   // volts row

    int z2 = 0, z4 = 0, z5 = 0;          // prev-step bits — uniform scalars

    // ---- cycle-detection: rolling-40 anchor + Brent pow-2 fallback ----
    float rav = 0.0f, rau = 0.0f; int raz2 = 0, raz4 = 0, raz5 = 0, ra_t = -1;
    float cav = 0.0f, cau = 0.0f; int caz2 = 0, caz4 = 0, caz5 = 0, ca_t = -1;
    int next_coarse = 8;
    int t_det = -1, Pf = 0;
    int blk5 = 0;   // t/8 mod 5; 0 <=> t % 40 == 0

    float zb[8], vb[8];

    int t = 0;
    for (; t + 8 <= T; t += 8) {
        // ---- block top: anchor compares / refresh (R9 semantics) ----
        if (blk5 == 0) {
            if (ra_t >= 0) {
                unsigned long long mv =
                    __ballot(__float_as_uint(v) == __float_as_uint(rav));
                unsigned long long mu =
                    __ballot(__float_as_uint(u) == __float_as_uint(rau));
                if (((mv & mu) & 0x1FFull) == 0x1FFull &&
                    z2 == raz2 && z4 == raz4 && z5 == raz5) {
                    t_det = t; Pf = t - ra_t;   // Pf == 40
                    break;
                }
            }
            if (t) { rav = v; rau = u; raz2 = z2; raz4 = z4; raz5 = z5; ra_t = t; }
        } else if (ca_t >= 0) {
            unsigned long long mv =
                __ballot(__float_as_uint(v) == __float_as_uint(cav));
            unsigned long long mu =
                __ballot(__float_as_uint(u) == __float_as_uint(cau));
            if (((mv & mu) & 0x1FFull) == 0x1FFull &&
                z2 == caz2 && z4 == caz4 && z5 == caz5) {
                t_det = t; Pf = t - ca_t;
                break;
            }
        }
        if (t == next_coarse) {
            cav = v; cau = u; caz2 = z2; caz4 = z4; caz5 = z5; ca_t = t;
            next_coarse <<= 1;
        }
        blk5 = (blk5 == 4) ? 0 : (blk5 + 1);

        #pragma unroll
        for (int j = 0; j < 8; ++j) {
            // speculative I from prev-step bits (off critical path):
            // uniform ternaries -> s_cselect mask + v_cndmask chains
            float fI2 = z4 ? (z2 ? I2_11 : I2_01) : (z2 ? I2_10 : I2_00);
            float Ibs = z5 ? Ib_b : Ib_a;
            float Ib  = isLLBN ? fI2 : Ibs;

            // izh head (I-independent)
            float t1 = 0.04f * v;
            float t2 = t1 * v;
            float t3 = 5.0f * v;
            float t4 = t2 + t3;
            float t5 = t4 + 140.0f;
            float t6 = t5 - u;
            float bv = b * v;
            float bvu = bv - u;
            float du = ka * bvu;
            float u1 = u + du;
            float u1d = u1 + d;

            // speculative tail + single ballot
            float t7 = t6 + Ib;
            float dv = 0.25f * t7;       // TAU*DT = 0.25 exactly
            float v1 = v + dv;
            float v1p = dpp_swap1(v1);   // partner's candidate v1
            bool fa  = (v1  >= 30.0f);
            bool fap = (v1p >= 30.0f);
            unsigned long long m = __ballot(fa);

            // uniform resolve (shallow SALU, no dynamic shifts)
            unsigned mlo = (unsigned)m;
            int nz2 = (int)((mlo >> 8) & 1u);
            int z3  = nz2 ? (int)((mlo >> 1) & 1u) : (int)(mlo & 1u);
            int nz4 = z3 ? (int)((mlo >> 3) & 1u) : (int)((mlo >> 2) & 1u);
            int nz5 = z3 ? (int)((mlo >> 5) & 1u) : (int)((mlo >> 4) & 1u);
            unsigned pm32 = (nz2 ? 0x01u : 0x02u)
                          | (z3  ? 0x14u : 0x28u)
                          | (nz5 ? 0x40u : 0x80u);
            bool take_p = (pm32 & lane_bit) != 0u;

            // finalize BOTH variants locally, then ONE cndmask per state var
            float wv  = fa  ? c : v1;
            float wvp = fap ? c : v1p;
            float uc  = fa  ? u1d : u1;    // u1/u1d are pair-identical
            float ucp = fap ? u1d : u1;
            v = take_p ? wvp : wv;
            u = take_p ? ucp : uc;
            zb[j] = take_p ? (fap ? 1.0f : 0.0f) : (fa ? 1.0f : 0.0f);
            vb[j] = v;

            z2 = nz2; z4 = nz4; z5 = nz5;
        }
        // batched flush (rows 16B-aligned at t; t % 8 == 0); pair lanes
        // store duplicate identical values (same wave, same data) — benign
        *(float4*)(psp)     = make_float4(zb[0], zb[1], zb[2], zb[3]);
        *(float4*)(psp + 4) = make_float4(zb[4], zb[5], zb[6], zb[7]);
        *(float4*)(pvv)     = make_float4(vb[0], vb[1], vb[2], vb[3]);
        *(float4*)(pvv + 4) = make_float4(vb[4], vb[5], vb[6], vb[7]);
        psp += 8;
        pvv += 8;
    }
    // tail (T not divisible by 8), only when no cycle was detected
    for (; t < T && t_det < 0; ++t) {
        float fI2 = z4 ? (z2 ? I2_11 : I2_01) : (z2 ? I2_10 : I2_00);
        float Ibs = z5 ? Ib_b : Ib_a;
        float Ib  = isLLBN ? fI2 : Ibs;
        float t1 = 0.04f * v;
        float t2 = t1 * v;
        float t3 = 5.0f * v;
        float t4 = t2 + t3;
        float t5 = t4 + 140.0f;
        float t6 = t5 - u;
        float bv = b * v;
        float bvu = bv - u;
        float du = ka * bvu;
        float u1 = u + du;
        float u1d = u1 + d;
        float t7 = t6 + Ib;
        float dv = 0.25f * t7;
        float v1 = v + dv;
        float v1p = dpp_swap1(v1);
        bool fa  = (v1  >= 30.0f);
        bool fap = (v1p >= 30.0f);
        unsigned long long m = __ballot(fa);
        unsigned mlo = (unsigned)m;
        int nz2 = (int)((mlo >> 8) & 1u);
        int z3  = nz2 ? (int)((mlo >> 1) & 1u) : (int)(mlo & 1u);
        int nz4 = z3 ? (int)((mlo >> 3) & 1u) : (int)((mlo >> 2) & 1u);
        int nz5 = z3 ? (int)((mlo >> 5) & 1u) : (int)((mlo >> 4) & 1u);
        unsigned pm32 = (nz2 ? 0x01u : 0x02u)
                      | (z3  ? 0x14u : 0x28u)
                      | (nz5 ? 0x40u : 0x80u);
        bool take_p = (pm32 & lane_bit) != 0u;
        float wv  = fa  ? c : v1;
        float wvp = fap ? c : v1p;
        float uc  = fa  ? u1d : u1;
        float ucp = fap ? u1d : u1;
        v = take_p ? wvp : wv;
        u = take_p ? ucp : uc;
        psp[0] = take_p ? (fap ? 1.0f : 0.0f) : (fa ? 1.0f : 0.0f);
        pvv[0] = v;
        ++psp; ++pvv;
        z2 = nz2; z4 = nz4; z5 = nz5;
    }

    // publish detection result (ws is re-poisoned before every call)
    if (lane == 0) {
        ws[0] = (t_det >= 0) ? 1 : 0;
        ws[1] = t_det;
        ws[2] = Pf;
    }
}

// Fills out[r, t] for t in [t_det, T) with the periodic continuation
// out[r, t_det - P + ((t - t_det) mod P)]. No-op when no cycle was found.
__global__ __launch_bounds__(256) void fill_cycle(float* __restrict__ out,
                                                  const int* __restrict__ ws,
                                                  int T) {
    if (ws[0] == 0) return;
    const int t0 = ws[1];
    const int P  = ws[2];
    const int r  = blockIdx.y;                    // 0..9 (row)
    const float* __restrict__ src = out + (size_t)r * T + (t0 - P);
    float* __restrict__ dst       = out + (size_t)r * T + t0;
    const int n = T - t0;
    for (int i = blockIdx.x * blockDim.x + threadIdx.x; i < n;
         i += gridDim.x * blockDim.x) {
        dst[i] = src[i % P];
    }
}

extern "C" void kernel_launch(void* const* d_in, const int* in_sizes, int n_in,
                              void* d_out, int out_size, void* d_ws, size_t ws_size,
                              hipStream_t stream) {
    const float* mat = (const float*)d_in[0];
    const float* w   = (const float*)d_in[1];
    // out_size = 2 outputs * 5 neurons * T  -> T = out_size/10
    int T = out_size / 10;
    net_sim<<<1, 256, 0, stream>>>(mat, w, (float*)d_out, (int*)d_ws, T);
    dim3 grid(40, 10, 1);
    fill_cycle<<<grid, 256, 0, stream>>>((float*)d_out, (const int*)d_ws, T);
}

// Round 5
// 293.300 us; speedup vs baseline: 1.0258x; 1.0089x over previous
//
#include <hip/hip_runtime.h>

// Exact-order float32 arithmetic: numpy/jax evaluate left-to-right with no
// FMA contraction. hipcc defaults to -ffp-contract=fast, which would change
// rounding -> possible spike-time shift -> large voltage absmax error.
#pragma clang fp contract(off)

// R18 = R13 (best harness-verified: 272-276 us/dispatch, absmax 0.0)
// + the single provably-exact fusion: v1 = fmaf(0.25f, t7, v).
//   0.25*t7 is exact (power-of-two scale, no subnormal range here), so
//   round(round(0.25*t7) + v) == round(0.25*t7 + v): bitwise identical,
//   one dependent VALU op shorter. Explicit fmaf() fuses even under
//   fp contract(off) (pragma only bars compiler-introduced contraction).
// Applied in the speculative tail, the actual tail, and the scalar tail.
// Everything else is R13 verbatim (lane map, ballot resolve, sel_mask,
// rolling-40 + Brent detection, batched float4 flush, fill_cycle).
// R16 (select-don't-recompute) measured worse (293 vs 274); R17 (2-step
// speculation) failed absmax — both abandoned.
// Lane map (wave 0):
//   0   : LLBN (no speculation: I2 depends only on prev-step bits)
//   1,2 : EBN  speculating z2 = 0,1
//   3,4 : IFN  speculating z3 = 0,1
//   5,6 : TN   speculating z3 = 0,1   (known z5p folded into candidates)
//   7,8 : MN   speculating z5 = 0,1
// Per step: candidate-I prep -> common izh head -> speculative ballot tail
// -> scalar resolve (z2,z3,z4,z5) -> actual tail recomputed locally with
// the I selected by an SGPR-pair-mask cndmask -> fire/reset -> buffered
// stores (float4 flush per 8 steps).
// Cycle detection: state = {v,u} x 9 lanes + carry bits. Bitwise equality
// with a 40-step-old rolling anchor (checked when the block counter wraps,
// i.e. t % 40 == 0) => outputs repeat [t-40, t); Brent pow-2 anchors as
// generic fallback at the other block tops. fill_cycle copies the
// periodic continuation.

__device__ __forceinline__ float sel_mask(float a, float b, unsigned long long m) {
    float r;
    // D = m.bit[lane] ? S1 : S0   (VOP3 v_cndmask with SGPR-pair condition)
    asm("v_cndmask_b32 %0, %1, %2, %3" : "=v"(r) : "v"(a), "v"(b), "s"(m));
    return r;
}

__global__ __launch_bounds__(256) void net_sim(const float* __restrict__ mat,
                                               const float* __restrict__ w,
                                               float* __restrict__ out,
                                               int* __restrict__ ws,
                                               int T) {
    __shared__ double red[256];
    const int tid = threadIdx.x;

    // ---- z_plus = sum(input_mat * w0), f32 products accumulated in f64 ----
    const float w0 = w[0];
    double s = 0.0;
    for (int i = tid; i < 127 * 127; i += 256) {
        float p = mat[i] * w0;   // elementwise product rounded to f32 (as ref)
        s += (double)p;
    }
    red[tid] = s;
    __syncthreads();
    #pragma unroll
    for (int off = 128; off > 0; off >>= 1) {
        if (tid < off) red[tid] += red[tid + off];
        __syncthreads();
    }
    if (tid >= 9) return;   // 9 lanes of wave 0 continue; no more barriers

    const float z_plus = (float)red[0];

    const float w2 = w[2], w3 = w[3], w5 = w[5], w6 = w[6], w7 = w[7],
                w8 = w[8], w9 = w[9], w10 = w[10], w11 = w[11];
    const float zp_w1 = z_plus * w[1];
    const float zp_w4 = z_plus * w[4];

    // Validated constant-I set (R2..R12, absmax 0.0). z*w is exactly +0.0f
    // or w; x + (+0.0f) == x for the values involved.
    const float I2_00 = w2 * (zp_w1 - 0.0f) + w3 * 0.0f;   // (z2p, z4p)
    const float I2_10 = w2 * (zp_w1 - 0.0f) + w3 * 1.0f;
    const float I2_01 = w2 * (zp_w1 - w7)   + w3 * 0.0f;
    const float I2_11 = w2 * (zp_w1 - w7)   + w3 * 1.0f;
    const float I3_0  = zp_w4 + 0.0f * w5;
    const float I3_1  = zp_w4 + 1.0f * w5;
    const float I4_0  = 0.0f * w6;
    const float I4_1  = 1.0f * w6;
    const float I5_00 = w9 * (0.0f * w8) + w10 * 0.0f;     // (z3, z5p)
    const float I5_10 = w9 * (1.0f * w8) + w10 * 0.0f;
    const float I5_01 = w9 * (0.0f * w8) + w10 * 1.0f;
    const float I5_11 = w9 * (1.0f * w8) + w10 * 1.0f;
    const float I6_0  = 0.0f * w11;
    const float I6_1  = 1.0f * w11;

    const int lane = tid;  // 0..8
    const int g = lane == 0 ? 0 : lane <= 2 ? 1 : lane <= 4 ? 2 : lane <= 6 ? 3 : 4;

    // per-lane params; ka = float(TAU*DT*a) computed in f64 like Python
    const float ka = lane == 0 ? (float)(0.25 * 0.1) : (float)(0.25 * 0.02);
    const float b  = lane == 0 ? -0.075f : (g == 3 ? 0.2f : 0.25f);
    const float c  = g <= 1 ? -55.0f : -65.0f;
    const float d  = g == 1 ? 0.05f : 6.0f;
    float v = g == 0 ? -60.0f : (g == 3 ? -70.0f : -64.0f);
    float u = g == 0 ? 4.5f   : (g == 3 ? -14.0f : -16.0f);

    // candidate-I vectors: variant0/variant1 per group, for z5p=0(a)/1(b).
    const float C0a = g == 0 ? I2_00 : g == 1 ? I3_0 : g == 2 ? I4_0
                    : g == 3 ? I5_00 : I6_0;
    const float C0b = g == 0 ? I2_00 : g == 1 ? I3_0 : g == 2 ? I4_0
                    : g == 3 ? I5_01 : I6_0;
    const float C1a = g == 1 ? I3_1 : g == 2 ? I4_1 : g == 3 ? I5_10
                    : g == 4 ? I6_1 : 0.0f;
    const float C1b = g == 1 ? I3_1 : g == 2 ? I4_1 : g == 3 ? I5_11
                    : g == 4 ? I6_1 : 0.0f;

    const bool is_lane0  = (lane == 0);
    const bool spec_var1 = (lane == 2) | (lane == 4) | (lane == 6) | (lane == 8);

    float* __restrict__ psp = out + g * T;           // spikes row
    float* __restrict__ pvv = out + 5 * T + g * T;   // volts row

    int z2 = 0, z4 = 0, z5 = 0;   // prev-step bits (z2p, z4p, z5p) — uniform

    // ---- cycle-detection: rolling-40 anchor + Brent pow-2 fallback ----
    float rav = 0.0f, rau = 0.0f; int raz2 = 0, raz4 = 0, raz5 = 0, ra_t = -1;
    float cav = 0.0f, cau = 0.0f; int caz2 = 0, caz4 = 0, caz5 = 0, ca_t = -1;
    int next_coarse = 8;
    int t_det = -1, Pf = 0;
    int blk5 = 0;   // t/8 mod 5; 0 <=> t % 40 == 0

    float zb[8], vb[8];

    int t = 0;
    for (; t + 8 <= T; t += 8) {
        // ---- block top: anchor compares / refresh (R9 semantics) ----
        if (blk5 == 0) {
            if (ra_t >= 0) {
                unsigned long long mv =
                    __ballot(__float_as_uint(v) == __float_as_uint(rav));
                unsigned long long mu =
                    __ballot(__float_as_uint(u) == __float_as_uint(rau));
                if (((mv & mu) & 0x1FFull) == 0x1FFull &&
                    z2 == raz2 && z4 == raz4 && z5 == raz5) {
                    t_det = t; Pf = t - ra_t;   // Pf == 40
                    break;
                }
            }
            if (t) { rav = v; rau = u; raz2 = z2; raz4 = z4; raz5 = z5; ra_t = t; }
        } else if (ca_t >= 0) {
            unsigned long long mv =
                __ballot(__float_as_uint(v) == __float_as_uint(cav));
            unsigned long long mu =
                __ballot(__float_as_uint(u) == __float_as_uint(cau));
            if (((mv & mu) & 0x1FFull) == 0x1FFull &&
                z2 == caz2 && z4 == caz4 && z5 == caz5) {
                t_det = t; Pf = t - ca_t;
                break;
            }
        }
        if (t == next_coarse) {
            cav = v; cau = u; caz2 = z2; caz4 = z4; caz5 = z5; ca_t = t;
            next_coarse <<= 1;
        }
        blk5 = (blk5 == 4) ? 0 : (blk5 + 1);

        #pragma unroll
        for (int j = 0; j < 8; ++j) {
            // candidate-I prep from prev-step bits (off critical path)
            float fI2 = z4 ? (z2 ? I2_11 : I2_01) : (z2 ? I2_10 : I2_00);
            float V0 = z5 ? C0b : C0a;
            float V1 = z5 ? C1b : C1a;
            V0 = is_lane0 ? fI2 : V0;
            float Ib = spec_var1 ? V1 : V0;

            // common izh head (I-independent)
            float t1 = 0.04f * v;
            float t2 = t1 * v;
            float t3 = 5.0f * v;
            float t4 = t2 + t3;
            float t5 = t4 + 140.0f;
            float t6 = t5 - u;
            float bv = b * v;
            float bvu = bv - u;
            float du = ka * bvu;
            float u1 = u + du;

            // speculative (ballot) tail — fmaf(0.25,x,v) == v + (0.25f*x)
            // bitwise (0.25*x exact: pure exponent shift, no subnormals)
            float t7b = t6 + Ib;
            float v1b = fmaf(0.25f, t7b, v);   // TAU*DT = 0.25 exactly
            unsigned long long m = __ballot(v1b >= 30.0f);

            // scalar resolution (uniform)
            int nz2 = (int)(m & 1ull);
            int z3  = (int)((m >> (1 + nz2)) & 1ull);
            int nz4 = (int)((m >> (3 + z3)) & 1ull);
            int nz5 = (int)((m >> (5 + z3)) & 1ull);
            unsigned long long ssel =
                (nz2 ? 0x006ull : 0ull) | (z3 ? 0x078ull : 0ull)
              | (nz5 ? 0x180ull : 0ull);

            // actual tail, recomputed locally; I select via SGPR-pair mask
            float Ia = sel_mask(V0, V1, ssel);
            float t7a = t6 + Ia;
            float v1a = fmaf(0.25f, t7a, v);
            bool fa = (v1a >= 30.0f);
            v = fa ? c : v1a;
            float u1d = u1 + d;
            u = fa ? u1d : u1;           // z*d is exactly d or +0.0f

            zb[j] = fa ? 1.0f : 0.0f;
            vb[j] = v;

            z2 = nz2; z4 = nz4; z5 = nz5;
        }
        // batched flush (rows 16B-aligned at t; t % 8 == 0)
        *(float4*)(psp)     = make_float4(zb[0], zb[1], zb[2], zb[3]);
        *(float4*)(psp + 4) = make_float4(zb[4], zb[5], zb[6], zb[7]);
        *(float4*)(pvv)     = make_float4(vb[0], vb[1], vb[2], vb[3]);
        *(float4*)(pvv + 4) = make_float4(vb[4], vb[5], vb[6], vb[7]);
        psp += 8;
        pvv += 8;
    }
    // tail (T not divisible by 8), only when no cycle was detected
    for (; t < T && t_det < 0; ++t) {
        float fI2 = z4 ? (z2 ? I2_11 : I2_01) : (z2 ? I2_10 : I2_00);
        float V0 = z5 ? C0b : C0a;
        float V1 = z5 ? C1b : C1a;
        V0 = is_lane0 ? fI2 : V0;
        float Ib = spec_var1 ? V1 : V0;
        float t1 = 0.04f * v;
        float t2 = t1 * v;
        float t3 = 5.0f * v;
        float t4 = t2 + t3;
        float t5 = t4 + 140.0f;
        float t6 = t5 - u;
        float bv = b * v;
        float bvu = bv - u;
        float du = ka * bvu;
        float u1 = u + du;
        float t7b = t6 + Ib;
        float v1b = fmaf(0.25f, t7b, v);
        unsigned long long m = __ballot(v1b >= 30.0f);
        int nz2 = (int)(m & 1ull);
        int z3  = (int)((m >> (1 + nz2)) & 1ull);
        int nz4 = (int)((m >> (3 + z3)) & 1ull);
        int nz5 = (int)((m >> (5 + z3)) & 1ull);
        unsigned long long ssel =
            (nz2 ? 0x006ull : 0ull) | (z3 ? 0x078ull : 0ull)
          | (nz5 ? 0x180ull : 0ull);
        float Ia = sel_mask(V0, V1, ssel);
        float t7a = t6 + Ia;
        float v1a = fmaf(0.25f, t7a, v);
        bool fa = (v1a >= 30.0f);
        v = fa ? c : v1a;
        float u1d = u1 + d;
        u = fa ? u1d : u1;
        psp[0] = fa ? 1.0f : 0.0f;
        pvv[0] = v;
        ++psp; ++pvv;
        z2 = nz2; z4 = nz4; z5 = nz5;
    }

    // publish detection result (ws is re-poisoned before every call)
    if (lane == 0) {
        ws[0] = (t_det >= 0) ? 1 : 0;
        ws[1] = t_det;
        ws[2] = Pf;
    }
}

// Fills out[r, t] for t in [t_det, T) with the periodic continuation
// out[r, t_det - P + ((t - t_det) mod P)]. No-op when no cycle was found.
__global__ __launch_bounds__(256) void fill_cycle(float* __restrict__ out,
                                                  const int* __restrict__ ws,
                                                  int T) {
    if (ws[0] == 0) return;
    const int t0 = ws[1];
    const int P  = ws[2];
    const int r  = blockIdx.y;                    // 0..9 (row)
    const float* __restrict__ src = out + (size_t)r * T + (t0 - P);
    float* __restrict__ dst       = out + (size_t)r * T + t0;
    const int n = T - t0;
    for (int i = blockIdx.x * blockDim.x + threadIdx.x; i < n;
         i += gridDim.x * blockDim.x) {
        dst[i] = src[i % P];
    }
}

extern "C" void kernel_launch(void* const* d_in, const int* in_sizes, int n_in,
                              void* d_out, int out_size, void* d_ws, size_t ws_size,
                              hipStream_t stream) {
    const float* mat = (const float*)d_in[0];
    const float* w   = (const float*)d_in[1];
    // out_size = 2 outputs * 5 neurons * T  -> T = out_size/10
    int T = out_size / 10;
    net_sim<<<1, 256, 0, stream>>>(mat, w, (float*)d_out, (int*)d_ws, T);
    dim3 grid(40, 10, 1);
    fill_cycle<<<grid, 256, 0, stream>>>((float*)d_out, (const int*)d_ws, T);
}